// Round 4
// baseline (127.405 us; speedup 1.0000x reference)
//
#include <hip/hip_runtime.h>
#include <math.h>
#include <stdint.h>

#define VOCAB 100000
#define DIM   128
#define BATCH 16384
#define CMAX  10
#define KNEG  5

typedef float f32x4 __attribute__((ext_vector_type(4)));

// Numerically stable log(sigmoid(x)) = min(x,0) - log1p(exp(-|x|))
__device__ __forceinline__ float log_sigmoid(float x) {
    return fminf(x, 0.0f) - log1pf(expf(-fabsf(x)));
}

// DPP-based 32-lane sum: after 5 dependent VALU adds, lane 31 holds
// sum(lanes 0..31) and lane 63 holds sum(lanes 32..63).
#define DPP_ADD_STEP(v, ctrl)                                                  \
    v += __int_as_float(__builtin_amdgcn_update_dpp(                           \
        0, __float_as_int(v), (ctrl), 0xF, 0xF, false))

__device__ __forceinline__ float dpp_reduce32_to_lane31(float v) {
    DPP_ADD_STEP(v, 0x111);  // row_shr:1
    DPP_ADD_STEP(v, 0x112);  // row_shr:2
    DPP_ADD_STEP(v, 0x114);  // row_shr:4
    DPP_ADD_STEP(v, 0x118);  // row_shr:8
    DPP_ADD_STEP(v, 0x142);  // row_bcast:15
    return v;
}

// ---------------------------------------------------------------------------
// R4: software-pipelined waves. One wave owns 4 consecutive samples with a
// depth-2 pipeline: issue sample i+1's 9 wave-wide gathers BEFORE consuming
// sample i, so each wave holds 9-18 gather instrs in flight continuously
// (R3's waves held loads for only ~70% of a short life -> ~13 outstanding
// HBM misses/CU, the measured binding resource). Whole grid (4096 waves) is
// co-resident: zero wave churn. Index loads are scalar (lgkm domain), all
// result stores deferred past the final drain, so vmcnt counts exactly our
// gather instrs. Per-sample word mapping + fused loss identical to R3
// (proven): half h owns slots j=h*8..h*8+7, masked/dummy slots redirect to
// negw[0] (MSHR-dedup), j=15 dummy.
// ---------------------------------------------------------------------------

// Issue 9 wave-wide gathers for one sample: t row + 8 per-half rows.
#define ISSUE(twv, w, tv, rv)                                                  \
    {                                                                          \
        asm volatile("global_load_dwordx4 %0, %1, %2"                          \
                     : "=v"(tv)                                                \
                     : "v"((uint32_t)(twv) * 512u + sub16), "s"(in_emb));      \
        asm volatile("global_load_dwordx4 %0, %1, %2"                          \
                     : "=v"(rv[0])                                             \
                     : "v"((uint32_t)(w)[0] * 512u + sub16), "s"(out_emb));    \
        asm volatile("global_load_dwordx4 %0, %1, %2"                          \
                     : "=v"(rv[1])                                             \
                     : "v"((uint32_t)(w)[1] * 512u + sub16), "s"(out_emb));    \
        asm volatile("global_load_dwordx4 %0, %1, %2"                          \
                     : "=v"(rv[2])                                             \
                     : "v"((uint32_t)(w)[2] * 512u + sub16), "s"(out_emb));    \
        asm volatile("global_load_dwordx4 %0, %1, %2"                          \
                     : "=v"(rv[3])                                             \
                     : "v"((uint32_t)(w)[3] * 512u + sub16), "s"(out_emb));    \
        asm volatile("global_load_dwordx4 %0, %1, %2"                          \
                     : "=v"(rv[4])                                             \
                     : "v"((uint32_t)(w)[4] * 512u + sub16), "s"(out_emb));    \
        asm volatile("global_load_dwordx4 %0, %1, %2"                          \
                     : "=v"(rv[5])                                             \
                     : "v"((uint32_t)(w)[5] * 512u + sub16), "s"(out_emb));    \
        asm volatile("global_load_dwordx4 %0, %1, %2"                          \
                     : "=v"(rv[6])                                             \
                     : "v"((uint32_t)(w)[6] * 512u + sub16), "s"(out_emb));    \
        asm volatile("global_load_dwordx4 %0, %1, %2"                          \
                     : "=v"(rv[7])                                             \
                     : "v"((uint32_t)(w)[7] * 512u + sub16), "s"(out_emb));    \
    }

// Counted wait: N = instrs allowed to remain outstanding ("memory" clobber
// pins compiler memory ops outside the counted window).
#define WAITN(n, tv, rv)                                                       \
    asm volatile("s_waitcnt vmcnt(" #n ")"                                     \
                 : "+v"(tv), "+v"(rv[0]), "+v"(rv[1]), "+v"(rv[2]),            \
                   "+v"(rv[3]), "+v"(rv[4]), "+v"(rv[5]), "+v"(rv[6]),         \
                   "+v"(rv[7])                                                 \
                 :                                                             \
                 : "memory")

// Build the 8 per-half words for sample index i (compile-time i).
#define BUILD_WORDS(i, w)                                                      \
    {                                                                          \
        _Pragma("unroll")                                                      \
        for (int jj = 0; jj < 8; ++jj) {                                       \
            const int w0 = (jj < len_[i]) ? cw_[i][jj] : nw_[i][0];            \
            int w1;                                                            \
            if (jj < 2)      w1 = ((8 + jj) < len_[i]) ? cw_[i][8 + jj]        \
                                                       : nw_[i][0];            \
            else if (jj < 7) w1 = nw_[i][jj - 2];                              \
            else             w1 = nw_[i][0];                                   \
            (w)[jj] = half ? w1 : w0;                                          \
        }                                                                      \
    }

// Dot + reduce + fused loss for one sample; writes float2 `res`.
#define CONSUME(tv, rv, len, res)                                              \
    {                                                                          \
        float p[8];                                                            \
        _Pragma("unroll")                                                      \
        for (int jj = 0; jj < 8; ++jj) {                                       \
            float d = tv.x * rv[jj].x + tv.y * rv[jj].y +                      \
                      tv.z * rv[jj].z + tv.w * rv[jj].w;                       \
            p[jj] = dpp_reduce32_to_lane31(d);                                 \
        }                                                                      \
        float bc[8];                                                           \
        _Pragma("unroll")                                                      \
        for (int jj = 0; jj < 8; ++jj) bc[jj] = __shfl(p[jj], 31, 32);         \
        const int sel = sub & 7;                                               \
        float a0 = (sel & 1) ? bc[1] : bc[0];                                  \
        float a1 = (sel & 1) ? bc[3] : bc[2];                                  \
        float a2 = (sel & 1) ? bc[5] : bc[4];                                  \
        float a3 = (sel & 1) ? bc[7] : bc[6];                                  \
        float b0_ = (sel & 2) ? a1 : a0;                                       \
        float b1_ = (sel & 2) ? a3 : a2;                                       \
        float sv = (sel & 4) ? b1_ : b0_;                                      \
        const int  j        = half * 8 + sel;                                  \
        const bool neg_slot = (j >= CMAX) && (j < CMAX + KNEG);                \
        const bool active   = (sub < 8);                                       \
        float v    = log_sigmoid(neg_slot ? -sv : sv);                         \
        float posc = (active && j < (len)) ? v : 0.0f;                         \
        float negc = (active && neg_slot)  ? v : 0.0f;                         \
        posc += __shfl_xor(posc, 1, 64);                                       \
        posc += __shfl_xor(posc, 2, 64);                                       \
        posc += __shfl_xor(posc, 4, 64);                                       \
        posc += __shfl_xor(posc, 32, 64);                                      \
        negc += __shfl_xor(negc, 1, 64);                                       \
        negc += __shfl_xor(negc, 2, 64);                                       \
        negc += __shfl_xor(negc, 4, 64);                                       \
        negc += __shfl_xor(negc, 32, 64);                                      \
        if ((len) > 0) {                                                       \
            res.x = -posc / (float)(len);                                      \
            res.y = -negc * (1.0f / KNEG);                                     \
        } else {                                                               \
            res.x = 0.0f;                                                      \
            res.y = 0.0f;                                                      \
        }                                                                      \
    }

__global__ __launch_bounds__(256) void score_loss_kernel(
    const int*   __restrict__ tgt,
    const int*   __restrict__ ctx,
    const int*   __restrict__ lens,
    const int*   __restrict__ neg,
    const float* __restrict__ in_emb,
    const float* __restrict__ out_emb,
    float2*      __restrict__ per_sample,  // ws: [BATCH]
    float*       __restrict__ out)
{
    const int tid  = threadIdx.x;
    const int lane = tid & 63;
    const int sub  = lane & 31;              // lane within half-wave
    const int half = lane >> 5;              // which 8-score group
    const int wid  = __builtin_amdgcn_readfirstlane((blockIdx.x * 256 + tid) >> 6);
    const int b0   = wid * 4;                // 4 consecutive samples per wave

    if (blockIdx.x == 0 && tid < 2) out[tid] = 0.0f;

    // ---- scalar index loads for all 4 samples (uniform -> s_load, lgkm) ----
    int len_[4], tw_[4];
    int cw_[4][CMAX], nw_[4][KNEG];
#pragma unroll
    for (int i = 0; i < 4; ++i) {
        len_[i] = lens[b0 + i];
        tw_[i]  = tgt[b0 + i];
#pragma unroll
        for (int c = 0; c < CMAX; ++c) cw_[i][c] = ctx[(b0 + i) * CMAX + c];
#pragma unroll
        for (int k = 0; k < KNEG; ++k) nw_[i][k] = neg[(b0 + i) * KNEG + k];
    }

    const uint32_t sub16 = (uint32_t)sub * 16u;

    // Drain: after this, vmcnt counts exactly our ISSUE gathers.
    asm volatile("s_waitcnt vmcnt(0)" ::: "memory");

    f32x4 tvA, rvA[8], tvB, rvB[8];
    int   wA[8], wB[8];
    float2 res0, res1, res2, res3;

    // ---- depth-2 software pipeline over 4 samples ----
    BUILD_WORDS(0, wA); ISSUE(tw_[0], wA, tvA, rvA);
    BUILD_WORDS(1, wB); ISSUE(tw_[1], wB, tvB, rvB);

    WAITN(9, tvA, rvA);                 // stage 0 landed; stage 1 in flight
    CONSUME(tvA, rvA, len_[0], res0);
    BUILD_WORDS(2, wA); ISSUE(tw_[2], wA, tvA, rvA);

    WAITN(9, tvB, rvB);                 // stage 1 landed; stage 2 in flight
    CONSUME(tvB, rvB, len_[1], res1);
    BUILD_WORDS(3, wB); ISSUE(tw_[3], wB, tvB, rvB);

    WAITN(9, tvA, rvA);                 // stage 2 landed; stage 3 in flight
    CONSUME(tvA, rvA, len_[2], res2);

    WAITN(0, tvB, rvB);                 // final drain
    CONSUME(tvB, rvB, len_[3], res3);

    // ---- stores only after the final drain (keep vmcnt counting exact) ----
    if (lane == 0) {
        per_sample[b0 + 0] = res0;
        per_sample[b0 + 1] = res1;
        per_sample[b0 + 2] = res2;
        per_sample[b0 + 3] = res3;
    }
}

// ---------------------------------------------------------------------------
// Kernel B: one thread per sample, reads 128 KB of float2 from L2.
// ---------------------------------------------------------------------------
__global__ __launch_bounds__(256) void reduce_kernel(
    const float2* __restrict__ per_sample,
    float*        __restrict__ out)
{
    const int tid = threadIdx.x;
    const int b   = blockIdx.x * 256 + tid;   // 64 blocks cover BATCH exactly

    const float2 pr = per_sample[b];
    float pos = pr.x;
    float neg = pr.y;

#pragma unroll
    for (int m = 32; m >= 1; m >>= 1) {
        pos += __shfl_xor(pos, m, 64);
        neg += __shfl_xor(neg, m, 64);
    }
    __shared__ float s_pos[4];
    __shared__ float s_neg[4];
    const int wave = tid >> 6;
    if ((tid & 63) == 0) { s_pos[wave] = pos; s_neg[wave] = neg; }
    __syncthreads();
    if (tid == 0) {
        float ps = s_pos[0] + s_pos[1] + s_pos[2] + s_pos[3];
        float ns = s_neg[0] + s_neg[1] + s_neg[2] + s_neg[3];
        atomicAdd(&out[0], ps * (1.0f / BATCH));
        atomicAdd(&out[1], ns * (1.0f / BATCH));
    }
}

extern "C" void kernel_launch(void* const* d_in, const int* in_sizes, int n_in,
                              void* d_out, int out_size, void* d_ws, size_t ws_size,
                              hipStream_t stream) {
    const int*   tgt     = (const int*)  d_in[0];
    const int*   ctx     = (const int*)  d_in[1];
    const int*   lens    = (const int*)  d_in[2];
    const int*   neg     = (const int*)  d_in[3];
    const float* in_emb  = (const float*)d_in[4];
    const float* out_emb = (const float*)d_in[5];
    float* out          = (float*)d_out;
    float2* per_sample  = (float2*)d_ws;      // BATCH * 8 B = 128 KiB scratch

    // one wave per 4 samples: 1024 blocks x 4 waves x 4 samples = 16384
    score_loss_kernel<<<BATCH / 16, 256, 0, stream>>>(
        tgt, ctx, lens, neg, in_emb, out_emb, per_sample, out);

    reduce_kernel<<<BATCH / 256, 256, 0, stream>>>(per_sample, out);
}

// Round 5
// 127.212 us; speedup vs baseline: 1.0015x; 1.0015x over previous
//
#include <hip/hip_runtime.h>
#include <math.h>
#include <stdint.h>

#define VOCAB 100000
#define DIM   128
#define BATCH 16384
#define CMAX  10
#define KNEG  5

typedef float f32x4 __attribute__((ext_vector_type(4)));

// Numerically stable log(sigmoid(x)) = min(x,0) - log1p(exp(-|x|))
__device__ __forceinline__ float log_sigmoid(float x) {
    return fminf(x, 0.0f) - log1pf(expf(-fabsf(x)));
}

// DPP-based 32-lane sum: after 5 dependent VALU adds, lane 31 holds
// sum(lanes 0..31) and lane 63 holds sum(lanes 32..63).
#define DPP_ADD_STEP(v, ctrl)                                                  \
    v += __int_as_float(__builtin_amdgcn_update_dpp(                           \
        0, __float_as_int(v), (ctrl), 0xF, 0xF, false))

__device__ __forceinline__ float dpp_reduce32_to_lane31(float v) {
    DPP_ADD_STEP(v, 0x111);  // row_shr:1
    DPP_ADD_STEP(v, 0x112);  // row_shr:2
    DPP_ADD_STEP(v, 0x114);  // row_shr:4
    DPP_ADD_STEP(v, 0x118);  // row_shr:8
    DPP_ADD_STEP(v, 0x142);  // row_bcast:15
    return v;
}

// ---------------------------------------------------------------------------
// R5: request-count reduction. Model from R1/R4 nulls: every gather is an
// L1-miss line-request occupying a TCP/MSHR slot for its downstream latency
// (~20 cy/line effective); waves cannot push the memory system harder, so
// time scales with ISSUED LINE-REQUESTS. R3/R4 always issued 16 row-slots
// per sample; only len+5 (avg 10) are needed. len is wave-uniform, so a
// switch(len) with 11 straight-line template bodies (all indices
// compile-time, rule #20) issues exactly 1 + ceil((len+5)/2) full-wave
// gathers: half 0 loads even rows, half 1 odd rows of the packed
// [ctx[0..len-1], neg[0..4]] row list. Odd counts pad with a dup of
// negw[4] (MSHR-merged). Expected ~-35% line-requests.
// ---------------------------------------------------------------------------
template<int LEN>
__device__ __forceinline__ void body(
    int t_word, const int (&ctxw)[CMAX], const int (&negw)[KNEG],
    const float* __restrict__ in_emb, const float* __restrict__ out_emb,
    int sub, int half, uint32_t sub16, float2& res)
{
    constexpr int ROWS  = LEN + KNEG;          // valid rows (6..15)
    constexpr int SLOTS = (ROWS + 1) & ~1;     // padded even (6..16)
    constexpr int NI    = SLOTS / 2;           // row-load instrs (3..8)

    // packed row word list; all indices compile-time after unroll
    int wr[SLOTS];
#pragma unroll
    for (int r = 0; r < SLOTS; ++r) {
        const int ci  = (r < CMAX) ? r : 0;                  // safe ctx idx
        int       ni  = (r >= LEN) ? (r - LEN) : 0;          // safe neg idx
        ni = (ni > KNEG - 1) ? (KNEG - 1) : ni;              // pad -> negw[4]
        wr[r] = (r < LEN) ? ctxw[ci] : negw[ni];
    }

    // per-instr word: half 0 -> even row, half 1 -> odd row
    int w[NI];
#pragma unroll
    for (int jj = 0; jj < NI; ++jj)
        w[jj] = half ? wr[2 * jj + 1] : wr[2 * jj];

    // ---- issue t + NI row gathers back-to-back, one vmcnt(0) ----
    f32x4 tv;
    asm volatile("global_load_dwordx4 %0, %1, %2"
                 : "=v"(tv)
                 : "v"((uint32_t)t_word * 512u + sub16), "s"(in_emb));
    f32x4 rv[NI];
#pragma unroll
    for (int jj = 0; jj < NI; ++jj) {
        asm volatile("global_load_dwordx4 %0, %1, %2"
                     : "=v"(rv[jj])
                     : "v"((uint32_t)w[jj] * 512u + sub16), "s"(out_emb));
    }
    asm volatile("s_waitcnt vmcnt(0)" ::: "memory");
    __builtin_amdgcn_sched_barrier(0);        // rule #18: pin consumers below

    // ---- dots + per-half DPP reduce; bc[jj]: lanes<32 get row 2jj,
    //      lanes>=32 get row 2jj+1 ----
    float bc[8];
#pragma unroll
    for (int jj = 0; jj < 8; ++jj) bc[jj] = 0.0f;
#pragma unroll
    for (int jj = 0; jj < NI; ++jj) {
        float d = tv.x * rv[jj].x + tv.y * rv[jj].y +
                  tv.z * rv[jj].z + tv.w * rv[jj].w;
        float p = dpp_reduce32_to_lane31(d);
        bc[jj] = __shfl(p, 31, 32);
    }

    // ---- 8-way mux: lane (half, sel) owns row r = 2*sel + half ----
    const int sel = sub & 7;
    float a0 = (sel & 1) ? bc[1] : bc[0];
    float a1 = (sel & 1) ? bc[3] : bc[2];
    float a2 = (sel & 1) ? bc[5] : bc[4];
    float a3 = (sel & 1) ? bc[7] : bc[6];
    float b0 = (sel & 2) ? a1 : a0;
    float b1 = (sel & 2) ? a3 : a2;
    float sv = (sel & 4) ? b1 : b0;

    const int  r      = 2 * sel + half;
    const bool is_neg = (r >= LEN);
    const bool active = (sub < 8) && (r < ROWS);

    float v    = log_sigmoid(is_neg ? -sv : sv);
    float posc = (active && !is_neg) ? v : 0.0f;
    float negc = (active &&  is_neg) ? v : 0.0f;

    // sum lanes {0..7} and {32..39}, then merge halves; total on lane 0
    posc += __shfl_xor(posc, 1, 64);
    posc += __shfl_xor(posc, 2, 64);
    posc += __shfl_xor(posc, 4, 64);
    posc += __shfl_xor(posc, 32, 64);
    negc += __shfl_xor(negc, 1, 64);
    negc += __shfl_xor(negc, 2, 64);
    negc += __shfl_xor(negc, 4, 64);
    negc += __shfl_xor(negc, 32, 64);

    res.x = -posc * (1.0f / (float)LEN);
    res.y = -negc * (1.0f / KNEG);
}

__global__ __launch_bounds__(256) void score_loss_kernel(
    const int*   __restrict__ tgt,
    const int*   __restrict__ ctx,
    const int*   __restrict__ lens,
    const int*   __restrict__ neg,
    const float* __restrict__ in_emb,
    const float* __restrict__ out_emb,
    float2*      __restrict__ per_sample,  // ws: [BATCH]
    float*       __restrict__ out)
{
    const int tid  = threadIdx.x;
    const int lane = tid & 63;
    const int sub  = lane & 31;              // lane within half-wave
    const int half = lane >> 5;
    const int b    = (blockIdx.x * 256 + tid) >> 6;   // one wave per sample
    const int bu   = __builtin_amdgcn_readfirstlane(b);

    if (blockIdx.x == 0 && tid < 2) out[tid] = 0.0f;

    // ---- scalar index loads (uniform address -> s_load, lgkm domain) ----
    const int len    = lens[bu];
    const int t_word = tgt[bu];
    int ctxw[CMAX];
#pragma unroll
    for (int c = 0; c < CMAX; ++c) ctxw[c] = ctx[bu * CMAX + c];
    int negw[KNEG];
#pragma unroll
    for (int k = 0; k < KNEG; ++k) negw[k] = neg[bu * KNEG + k];

    const uint32_t sub16 = (uint32_t)sub * 16u;
    float2 res; res.x = 0.0f; res.y = 0.0f;

    // wave-uniform switch: scalar branch, no exec divergence
    switch (len) {
    case 1:  body<1> (t_word, ctxw, negw, in_emb, out_emb, sub, half, sub16, res); break;
    case 2:  body<2> (t_word, ctxw, negw, in_emb, out_emb, sub, half, sub16, res); break;
    case 3:  body<3> (t_word, ctxw, negw, in_emb, out_emb, sub, half, sub16, res); break;
    case 4:  body<4> (t_word, ctxw, negw, in_emb, out_emb, sub, half, sub16, res); break;
    case 5:  body<5> (t_word, ctxw, negw, in_emb, out_emb, sub, half, sub16, res); break;
    case 6:  body<6> (t_word, ctxw, negw, in_emb, out_emb, sub, half, sub16, res); break;
    case 7:  body<7> (t_word, ctxw, negw, in_emb, out_emb, sub, half, sub16, res); break;
    case 8:  body<8> (t_word, ctxw, negw, in_emb, out_emb, sub, half, sub16, res); break;
    case 9:  body<9> (t_word, ctxw, negw, in_emb, out_emb, sub, half, sub16, res); break;
    case 10: body<10>(t_word, ctxw, negw, in_emb, out_emb, sub, half, sub16, res); break;
    default: break;                          // len == 0: res stays (0,0)
    }

    if (lane == 0) per_sample[b] = res;
}

// ---------------------------------------------------------------------------
// Kernel B: one thread per sample, reads 128 KB of float2 from L2.
// ---------------------------------------------------------------------------
__global__ __launch_bounds__(256) void reduce_kernel(
    const float2* __restrict__ per_sample,
    float*        __restrict__ out)
{
    const int tid = threadIdx.x;
    const int b   = blockIdx.x * 256 + tid;   // 64 blocks cover BATCH exactly

    const float2 pr = per_sample[b];
    float pos = pr.x;
    float neg = pr.y;

#pragma unroll
    for (int m = 32; m >= 1; m >>= 1) {
        pos += __shfl_xor(pos, m, 64);
        neg += __shfl_xor(neg, m, 64);
    }
    __shared__ float s_pos[4];
    __shared__ float s_neg[4];
    const int wave = tid >> 6;
    if ((tid & 63) == 0) { s_pos[wave] = pos; s_neg[wave] = neg; }
    __syncthreads();
    if (tid == 0) {
        float ps = s_pos[0] + s_pos[1] + s_pos[2] + s_pos[3];
        float ns = s_neg[0] + s_neg[1] + s_neg[2] + s_neg[3];
        atomicAdd(&out[0], ps * (1.0f / BATCH));
        atomicAdd(&out[1], ns * (1.0f / BATCH));
    }
}

extern "C" void kernel_launch(void* const* d_in, const int* in_sizes, int n_in,
                              void* d_out, int out_size, void* d_ws, size_t ws_size,
                              hipStream_t stream) {
    const int*   tgt     = (const int*)  d_in[0];
    const int*   ctx     = (const int*)  d_in[1];
    const int*   lens    = (const int*)  d_in[2];
    const int*   neg     = (const int*)  d_in[3];
    const float* in_emb  = (const float*)d_in[4];
    const float* out_emb = (const float*)d_in[5];
    float* out          = (float*)d_out;
    float2* per_sample  = (float2*)d_ws;      // BATCH * 8 B = 128 KiB scratch

    // one 64-lane wave per sample; 4 samples per 256-thread block
    score_loss_kernel<<<BATCH / 4, 256, 0, stream>>>(
        tgt, ctx, lens, neg, in_emb, out_emb, per_sample, out);

    reduce_kernel<<<BATCH / 256, 256, 0, stream>>>(per_sample, out);
}